// Round 6
// baseline (80.789 us; speedup 1.0000x reference)
//
#include <hip/hip_runtime.h>
#include <hip/hip_bf16.h>
#include <stdint.h>

// ---------------------------------------------------------------------------
// Fused MLP, bf16 MFMA (32x32x16). Round-6 structure:
//  * chunk-packed weights (1KB per (m-tile,k-tile) chunk; lane-linear
//    ds_read_b128, conflict-free by construction).
//  * 20 half-layer phases over 2 x 16KB double-buffered LDS (32KB total ->
//    4 blocks/CU residency, the round-6 lever). Stage issued at phase start,
//    vmcnt(0) drained at phase end (~1000 MFMA cycles later => ~free).
//  * activations live in registers (FA/FB ping-pong, build2 permlane
//    transpose); cond path: z=FB, z2=FA, no activation LDS.
//  * C/D layout (HW-verified m74/m101): col = lane&31 (batch row),
//    m = (reg&3)+8*(reg>>2)+4*(lane>>5).
// ---------------------------------------------------------------------------

typedef __attribute__((ext_vector_type(8)))  short short8;   // 8 x bf16 frag
typedef __attribute__((ext_vector_type(16))) float f32x16;   // 32x32 acc
typedef __attribute__((ext_vector_type(4)))  float float4v;

#define NTOT 262144

// chunk-packed ws layout (bytes). Region = M/32 x K/16 x 1KB.
#define CW0    0          // W0:   4t x 2kk  = 8KB
#define CWH(i) (8192 + (i) * 32768)   // Wh[i]: 4t x 8kk = 32KB, i=0..6
#define CWOUT  237568     // Wout: 1t x 8kk = 8KB (rows 16..31 zero)
#define CWC0   245760     // Wc0 cols 0..127: 4t x 8kk = 32KB
#define CWC1   278528     // Wc1:  2t x 8kk = 16KB
#define CWC2   294912     // Wc2:  1t x 4kk = 4KB (rows 3..31 zero)
#define WS_TOTAL 299008

__device__ __forceinline__ unsigned short f2bf(float v) {
  union { __hip_bfloat16 h; unsigned short u; } c;
  c.h = __float2bfloat16(v);
  return c.u;
}

// ---------------------------------------------------------------------------
// Weight prep: fp32 -> bf16 chunk packing. One 16B piece per thread.
// chunk c = t*NKT + kk at region base + c*1024; byte l*16 belongs to lane l:
// W[32t + (l&31)][16kk + 8*(l>>5) .. +7].
// ---------------------------------------------------------------------------
__global__ __launch_bounds__(256) void convw(
    const float* __restrict__ W0, const float* __restrict__ Wh,
    const float* __restrict__ Wout, const float* __restrict__ Wc0,
    const float* __restrict__ Wc1, const float* __restrict__ Wc2,
    unsigned char* __restrict__ ws) {
  int cid = blockIdx.x * 256 + threadIdx.x;
  if (cid >= WS_TOTAL / 16) return;
  int b = cid * 16;
  const float* src; int base, rows, SS, NKT;
  if (b < 8192)        { base = CW0;   src = W0;   rows = 128; SS = 32;  NKT = 2; }
  else if (b < 237568) { int i = (b - 8192) >> 15;
                         base = 8192 + (i << 15);
                         src = Wh + i * 16384;      rows = 128; SS = 128; NKT = 8; }
  else if (b < 245760) { base = CWOUT; src = Wout; rows = 16;  SS = 128; NKT = 8; }
  else if (b < 278528) { base = CWC0;  src = Wc0;  rows = 128; SS = 144; NKT = 8; }
  else if (b < 294912) { base = CWC1;  src = Wc1;  rows = 64;  SS = 128; NKT = 8; }
  else                 { base = CWC2;  src = Wc2;  rows = 3;   SS = 64;  NKT = 4; }
  int rel = b - base;
  int c   = rel >> 10;
  int t   = c / NKT, kk = c - t * NKT;
  int l   = (rel & 1023) >> 4;
  int n   = l & 31, g = l >> 5;
  int row = 32 * t + n, col = 16 * kk + 8 * g;
  unsigned w0 = 0, w1 = 0, w2 = 0, w3 = 0;
  if (row < rows) {
    const float* p = src + row * SS + col;
    w0 = (unsigned)f2bf(p[0]) | ((unsigned)f2bf(p[1]) << 16);
    w1 = (unsigned)f2bf(p[2]) | ((unsigned)f2bf(p[3]) << 16);
    w2 = (unsigned)f2bf(p[4]) | ((unsigned)f2bf(p[5]) << 16);
    w3 = (unsigned)f2bf(p[6]) | ((unsigned)f2bf(p[7]) << 16);
  }
  *(uint4*)(ws + b) = make_uint4(w0, w1, w2, w3);
}

// ---------------------------------------------------------------------------
// Helpers
// ---------------------------------------------------------------------------
__device__ __forceinline__ unsigned pk2(float a, float b) {
  unsigned d;
  asm("v_cvt_pk_bf16_f32 %0, %1, %2" : "=v"(d) : "v"(a), "v"(b));
  return d;
}

__device__ __forceinline__ short8 frag_s8(const unsigned (&f)[4]) {
  union { unsigned u[4]; short8 s; } c;
  c.u[0] = f[0]; c.u[1] = f[1]; c.u[2] = f[2]; c.u[3] = f[3];
  return c.s;
}

__device__ __forceinline__ void swap32(unsigned &a, unsigned &b) {
  asm("v_permlane32_swap_b32 %0, %1" : "+v"(a), "+v"(b));
}

// From acc (m-tile t) build next-layer B-frags kk'=2t (f0), 2t+1 (f1).
__device__ __forceinline__ void build2(const f32x16 &a,
                                       unsigned (&f0)[4], unsigned (&f1)[4]) {
  unsigned a00 = pk2(a[0], a[1]),   a01 = pk2(a[2], a[3]);
  unsigned b00 = pk2(a[4], a[5]),   b01 = pk2(a[6], a[7]);
  swap32(a00, b00); swap32(a01, b01);
  f0[0] = a00; f0[1] = a01; f0[2] = b00; f0[3] = b01;
  unsigned a10 = pk2(a[8],  a[9]),  a11 = pk2(a[10], a[11]);
  unsigned b10 = pk2(a[12], a[13]), b11 = pk2(a[14], a[15]);
  swap32(a10, b10); swap32(a11, b11);
  f1[0] = a10; f1[1] = a11; f1[2] = b10; f1[3] = b11;
}

// Async stage `bytes` (4096/8192/16384) from chunk-packed ws into LDS.
__device__ __forceinline__ void stage(const unsigned char* __restrict__ g,
                                      unsigned char* l, int bytes,
                                      int wv, int lane) {
  #pragma unroll
  for (int base = wv * 1024; base < bytes; base += 4096) {
    __builtin_amdgcn_global_load_lds(
        (const __attribute__((address_space(1))) void*)(g + base + lane * 16),
        (__attribute__((address_space(3))) void*)(l + base), 16, 0, 0);
  }
}

#define VMCNT_(N) asm volatile("s_waitcnt vmcnt(" #N ")" ::: "memory")
#define VMCNT(N) VMCNT_(N)
#define BAR() __builtin_amdgcn_s_barrier()
#define SETPRIO(x) __builtin_amdgcn_s_setprio(x)
#define MFMA(A_, B_, C_) __builtin_amdgcn_mfma_f32_32x32x16_bf16(A_, B_, C_, 0, 0, 0)

// Half-layer: 2 m-tiles (u=0,1), NKT k-tiles, 4 indep MFMA chains.
// lb = lds + bufoff + lane*16. Writes nxt frags hb..hb+3.
template <int NKT, bool RELU>
__device__ __forceinline__ void half_phase(const unsigned char* lb,
                                           const unsigned (&cur)[2][8][4],
                                           unsigned (&nxt)[2][8][4], int hb,
                                           const f32x16 &zero16) {
  f32x16 a[2][2];
  SETPRIO(1);
  #pragma unroll
  for (int kk = 0; kk < NKT; ++kk) {
    short8 wf0 = *(const short8*)(lb + kk * 1024);
    short8 wf1 = *(const short8*)(lb + NKT * 1024 + kk * 1024);
    if (kk == 0) {
      a[0][0] = MFMA(wf0, frag_s8(cur[0][0]), zero16);
      a[0][1] = MFMA(wf0, frag_s8(cur[1][0]), zero16);
      a[1][0] = MFMA(wf1, frag_s8(cur[0][0]), zero16);
      a[1][1] = MFMA(wf1, frag_s8(cur[1][0]), zero16);
    } else {
      a[0][0] = MFMA(wf0, frag_s8(cur[0][kk]), a[0][0]);
      a[0][1] = MFMA(wf0, frag_s8(cur[1][kk]), a[0][1]);
      a[1][0] = MFMA(wf1, frag_s8(cur[0][kk]), a[1][0]);
      a[1][1] = MFMA(wf1, frag_s8(cur[1][kk]), a[1][1]);
    }
  }
  SETPRIO(0);
  #pragma unroll
  for (int u = 0; u < 2; ++u)
    #pragma unroll
    for (int s = 0; s < 2; ++s) {
      if (RELU) {
        #pragma unroll
        for (int j = 0; j < 16; ++j) a[u][s][j] = fmaxf(a[u][s][j], 0.f);
      }
      build2(a[u][s], nxt[s][hb + 2 * u], nxt[s][hb + 2 * u + 1]);
    }
}

// L9 half: Wc0 cols 0..127 from LDS + cond k-tile (cols 128..143) from regs.
__device__ __forceinline__ void half_c9(const unsigned char* lb,
                                        const unsigned (&cur)[2][8][4],
                                        unsigned (&nxt)[2][8][4], int hb,
                                        const unsigned (&cw0)[4],
                                        const unsigned (&cw1)[4],
                                        const unsigned (&cf)[2][4],
                                        const f32x16 &zero16) {
  f32x16 a[2][2];
  SETPRIO(1);
  #pragma unroll
  for (int kk = 0; kk < 8; ++kk) {
    short8 wf0 = *(const short8*)(lb + kk * 1024);
    short8 wf1 = *(const short8*)(lb + 8192 + kk * 1024);
    if (kk == 0) {
      a[0][0] = MFMA(wf0, frag_s8(cur[0][0]), zero16);
      a[0][1] = MFMA(wf0, frag_s8(cur[1][0]), zero16);
      a[1][0] = MFMA(wf1, frag_s8(cur[0][0]), zero16);
      a[1][1] = MFMA(wf1, frag_s8(cur[1][0]), zero16);
    } else {
      a[0][0] = MFMA(wf0, frag_s8(cur[0][kk]), a[0][0]);
      a[0][1] = MFMA(wf0, frag_s8(cur[1][kk]), a[0][1]);
      a[1][0] = MFMA(wf1, frag_s8(cur[0][kk]), a[1][0]);
      a[1][1] = MFMA(wf1, frag_s8(cur[1][kk]), a[1][1]);
    }
  }
  a[0][0] = MFMA(frag_s8(cw0), frag_s8(cf[0]), a[0][0]);
  a[0][1] = MFMA(frag_s8(cw0), frag_s8(cf[1]), a[0][1]);
  a[1][0] = MFMA(frag_s8(cw1), frag_s8(cf[0]), a[1][0]);
  a[1][1] = MFMA(frag_s8(cw1), frag_s8(cf[1]), a[1][1]);
  SETPRIO(0);
  #pragma unroll
  for (int u = 0; u < 2; ++u)
    #pragma unroll
    for (int s = 0; s < 2; ++s)
      build2(a[u][s], nxt[s][hb + 2 * u], nxt[s][hb + 2 * u + 1]);  // no relu
}

// ---------------------------------------------------------------------------
// Main fused kernel. 256 threads = 4 waves; 64 rows/wave.
// LDS: 2 x 16KB double buffer (32KB) -> 4 blocks/CU. 20 phases; stage at
// phase start, vmcnt(0)+barrier at phase end.
// ---------------------------------------------------------------------------
__global__ __launch_bounds__(256, 2) void mlp_fused(
    const float* __restrict__ x, const float* __restrict__ cond,
    const float* __restrict__ wc0g, const unsigned char* __restrict__ ws,
    float* __restrict__ out) {
  __shared__ __align__(16) unsigned char lds[32768];

  const int tid  = threadIdx.x;
  const int lane = tid & 63;
  const int wv   = tid >> 6;
  const int g    = lane >> 5;
  const int n    = lane & 31;
  const int rowbase = blockIdx.x * 256 + wv * 64;
  const int r0 = rowbase + n;
  const int r1 = rowbase + 32 + n;
  const unsigned char* B0 = lds + lane * 16;
  const unsigned char* B1 = B0 + 16384;

  f32x16 zero16;
  #pragma unroll
  for (int j = 0; j < 16; ++j) zero16[j] = 0.f;

  unsigned FA[2][8][4], FB[2][8][4];   // [subtile][k-tile][word]

  // -- prologue: stage W0 full (8KB -> b0); x frags --------------------------
  stage(ws + CW0, lds, 8192, wv, lane);
  #pragma unroll
  for (int s = 0; s < 2; ++s) {
    int row = s ? r1 : r0;
    #pragma unroll
    for (int kk = 0; kk < 2; ++kk) {
      const float4v* p = (const float4v*)(x + row * 32 + kk * 16 + 8 * g);
      float4v u0 = p[0], u1 = p[1];
      FA[s][kk][0] = pk2(u0.x, u0.y);
      FA[s][kk][1] = pk2(u0.z, u0.w);
      FA[s][kk][2] = pk2(u1.x, u1.y);
      FA[s][kk][3] = pk2(u1.z, u1.w);
    }
  }
  VMCNT(0); BAR();

  // -- P0: L0 (both halves, b0); stage L1h0 -> b1 ----------------------------
  stage(ws + CWH(0), lds + 16384, 16384, wv, lane);
  half_phase<2, true>(B0,        FA, FB, 0, zero16);
  half_phase<2, true>(B0 + 4096, FA, FB, 4, zero16);
  VMCNT(0); BAR();

  // -- P1..P14: backbone halves, alternating buffers -------------------------
  stage(ws + CWH(0) + 16384, lds, 16384, wv, lane);            // P1
  half_phase<8, true>(B1, FB, FA, 0, zero16);                  // L1h0
  VMCNT(0); BAR();
  stage(ws + CWH(1), lds + 16384, 16384, wv, lane);            // P2
  half_phase<8, true>(B0, FB, FA, 4, zero16);                  // L1h1
  VMCNT(0); BAR();

  stage(ws + CWH(1) + 16384, lds, 16384, wv, lane);            // P3
  half_phase<8, true>(B1, FA, FB, 0, zero16);                  // L2h0
  VMCNT(0); BAR();
  stage(ws + CWH(2), lds + 16384, 16384, wv, lane);            // P4
  half_phase<8, true>(B0, FA, FB, 4, zero16);                  // L2h1
  VMCNT(0); BAR();

  stage(ws + CWH(2) + 16384, lds, 16384, wv, lane);            // P5
  half_phase<8, true>(B1, FB, FA, 0, zero16);                  // L3h0
  VMCNT(0); BAR();
  stage(ws + CWH(3), lds + 16384, 16384, wv, lane);            // P6
  half_phase<8, true>(B0, FB, FA, 4, zero16);                  // L3h1
  VMCNT(0); BAR();

  stage(ws + CWH(3) + 16384, lds, 16384, wv, lane);            // P7
  half_phase<8, true>(B1, FA, FB, 0, zero16);                  // L4h0
  VMCNT(0); BAR();
  stage(ws + CWH(4), lds + 16384, 16384, wv, lane);            // P8
  half_phase<8, true>(B0, FA, FB, 4, zero16);                  // L4h1
  VMCNT(0); BAR();

  stage(ws + CWH(4) + 16384, lds, 16384, wv, lane);            // P9
  half_phase<8, true>(B1, FB, FA, 0, zero16);                  // L5h0
  VMCNT(0); BAR();
  stage(ws + CWH(5), lds + 16384, 16384, wv, lane);            // P10
  half_phase<8, true>(B0, FB, FA, 4, zero16);                  // L5h1
  VMCNT(0); BAR();

  stage(ws + CWH(5) + 16384, lds, 16384, wv, lane);            // P11
  half_phase<8, true>(B1, FA, FB, 0, zero16);                  // L6h0
  VMCNT(0); BAR();
  stage(ws + CWH(6), lds + 16384, 16384, wv, lane);            // P12
  half_phase<8, true>(B0, FA, FB, 4, zero16);                  // L6h1
  VMCNT(0); BAR();

  stage(ws + CWH(6) + 16384, lds, 16384, wv, lane);            // P13
  half_phase<8, true>(B1, FB, FA, 0, zero16);                  // L7h0
  VMCNT(0); BAR();
  stage(ws + CWOUT, lds + 16384, 8192, wv, lane);              // P14
  half_phase<8, true>(B0, FB, FA, 4, zero16);                  // L7h1; h in FA
  VMCNT(0); BAR();

  // -- P15: Wout (b1, 1 m-tile, no act) -> uncond_x; CF; stage Wc0h0 -> b0 ---
  unsigned CF[2][4];
  {
    stage(ws + CWC0, lds, 16384, wv, lane);
    #pragma unroll
    for (int s = 0; s < 2; ++s) {
      const float4v* q = (const float4v*)(cond + (s ? r1 : r0) * 16 + 8 * g);
      float4v c0 = q[0], c1 = q[1];
      CF[s][0] = pk2(c0.x, c0.y); CF[s][1] = pk2(c0.z, c0.w);
      CF[s][2] = pk2(c1.x, c1.y); CF[s][3] = pk2(c1.z, c1.w);
    }
    f32x16 a0, a1;
    SETPRIO(1);
    #pragma unroll
    for (int kk = 0; kk < 8; ++kk) {
      short8 wf = *(const short8*)(B1 + kk * 1024);
      if (kk == 0) {
        a0 = MFMA(wf, frag_s8(FA[0][0]), zero16);
        a1 = MFMA(wf, frag_s8(FA[1][0]), zero16);
      } else {
        a0 = MFMA(wf, frag_s8(FA[0][kk]), a0);
        a1 = MFMA(wf, frag_s8(FA[1][kk]), a1);
      }
    }
    SETPRIO(0);
    *(float4v*)(out + r0 * 16 + 4 * g)     = (float4v){a0[0], a0[1], a0[2], a0[3]};
    *(float4v*)(out + r0 * 16 + 8 + 4 * g) = (float4v){a0[4], a0[5], a0[6], a0[7]};
    *(float4v*)(out + r1 * 16 + 4 * g)     = (float4v){a1[0], a1[1], a1[2], a1[3]};
    *(float4v*)(out + r1 * 16 + 8 + 4 * g) = (float4v){a1[4], a1[5], a1[6], a1[7]};
  }
  VMCNT(0); BAR();

  // -- P16: L9h0 (b0): Wc0 rows 0..63 + cond k-tile; stage Wc0h1 -> b1 -------
  {
    stage(ws + CWC0 + 16384, lds + 16384, 16384, wv, lane);
    unsigned CW0r[4], CW1r[4];
    #pragma unroll
    for (int u = 0; u < 2; ++u) {
      const float4v* pc = (const float4v*)(wc0g + (32 * u + n) * 144 + 128 + 8 * g);
      float4v q0 = pc[0], q1 = pc[1];
      unsigned* cw = u ? CW1r : CW0r;
      cw[0] = pk2(q0.x, q0.y); cw[1] = pk2(q0.z, q0.w);
      cw[2] = pk2(q1.x, q1.y); cw[3] = pk2(q1.z, q1.w);
    }
    half_c9(B0, FA, FB, 0, CW0r, CW1r, CF, zero16);
  }
  VMCNT(0); BAR();

  // -- P17: L9h1 (b1): Wc0 rows 64..127 + cond k-tile; stage Wc1 -> b0 -------
  {
    stage(ws + CWC1, lds, 16384, wv, lane);
    unsigned CW0r[4], CW1r[4];
    #pragma unroll
    for (int u = 0; u < 2; ++u) {
      const float4v* pc = (const float4v*)(wc0g + (32 * (2 + u) + n) * 144 + 128 + 8 * g);
      float4v q0 = pc[0], q1 = pc[1];
      unsigned* cw = u ? CW1r : CW0r;
      cw[0] = pk2(q0.x, q0.y); cw[1] = pk2(q0.z, q0.w);
      cw[2] = pk2(q1.x, q1.y); cw[3] = pk2(q1.z, q1.w);
    }
    half_c9(B1, FA, FB, 4, CW0r, CW1r, CF, zero16);
  }
  VMCNT(0); BAR();

  // -- P18: L10 (b0): z2 = relu(Wc1 * z), z in FB -> FA; stage Wc2 -> b1 -----
  stage(ws + CWC2, lds + 16384, 4096, wv, lane);
  half_phase<8, true>(B0, FB, FA, 0, zero16);
  VMCNT(0); BAR();

  // -- P19: L11 (b1): cond_x = Wc2 * z2 (3 rows), K=64 -----------------------
  {
    f32x16 a0, a1;
    #pragma unroll
    for (int kk = 0; kk < 4; ++kk) {
      short8 wf = *(const short8*)(B1 + kk * 1024);
      if (kk == 0) {
        a0 = MFMA(wf, frag_s8(FA[0][0]), zero16);
        a1 = MFMA(wf, frag_s8(FA[1][0]), zero16);
      } else {
        a0 = MFMA(wf, frag_s8(FA[0][kk]), a0);
        a1 = MFMA(wf, frag_s8(FA[1][kk]), a1);
      }
    }
    float* outc = out + (size_t)NTOT * 16;
    if (g == 0) {   // m = reg for regs 0..2
      outc[r0 * 3 + 0] = a0[0];
      outc[r0 * 3 + 1] = a0[1];
      outc[r0 * 3 + 2] = a0[2];
      outc[r1 * 3 + 0] = a1[0];
      outc[r1 * 3 + 1] = a1[1];
      outc[r1 * 3 + 2] = a1[2];
    }
  }
}

// ---------------------------------------------------------------------------
extern "C" void kernel_launch(void* const* d_in, const int* in_sizes, int n_in,
                              void* d_out, int out_size, void* d_ws, size_t ws_size,
                              hipStream_t stream) {
  const float* x    = (const float*)d_in[0];
  const float* cond = (const float*)d_in[1];
  const float* W0   = (const float*)d_in[2];
  const float* Wh   = (const float*)d_in[3];
  const float* Wout = (const float*)d_in[4];
  const float* Wc0  = (const float*)d_in[5];
  const float* Wc1  = (const float*)d_in[6];
  const float* Wc2  = (const float*)d_in[7];
  unsigned char* ws = (unsigned char*)d_ws;

  convw<<<dim3((WS_TOTAL / 16 + 255) / 256), dim3(256), 0, stream>>>(
      W0, Wh, Wout, Wc0, Wc1, Wc2, ws);
  mlp_fused<<<dim3(NTOT / 256), dim3(256), 0, stream>>>(
      x, cond, Wc0, ws, (float*)d_out);
}